// Round 6
// baseline (254.663 us; speedup 1.0000x reference)
//
#include <hip/hip_runtime.h>
#include <hip/hip_bf16.h>
#include <math.h>

// Problem dims
#define Bb 4
#define Sdim 2048
#define Ddim 512
#define RANK 32
#define Nn16 16
#define TOK (Bb * Sdim)   // 8192
#define NCh 64            // chunks along S
#define LCh (Sdim / NCh)  // 32 steps per chunk

using bf16x8 = __attribute__((ext_vector_type(8))) __bf16;
using f32x4  = __attribute__((ext_vector_type(4))) float;

__device__ __forceinline__ unsigned short f2bf(float f) {
    unsigned int u = __float_as_uint(f);
    u += 0x7fffu + ((u >> 16) & 1u);
    return (unsigned short)(u >> 16);
}
__device__ __forceinline__ float bf2f(unsigned short h) {
    return __uint_as_float(((unsigned int)h) << 16);
}

// async global->LDS, 16B per lane; lds base must be wave-uniform
#define GLD16(g, l) __builtin_amdgcn_global_load_lds( \
    (const __attribute__((address_space(1))) void*)(g), \
    (__attribute__((address_space(3))) void*)(l), 16, 0, 0)

__device__ __forceinline__ float softplus_f(float v) {
    return v > 20.f ? v : log1pf(__expf(v));
}

// ---------------------------------------------------------------------------
// PREP (one dispatch): grid (16,16,6), 256 threads.
//  z=0: Wp -> Wp_bf (rm cast) + Wall rows [0,512) = Wp^T
//  z=1: Wb -> Wbt
//  z=2: Wdbc [512][64] -> Wdbct [64][512]     (blocks x<2)
//  z=3: Wdt [32][512] -> Wdtt [512][32]       (blocks y==0)
//  z=4: LayerNorm -> xn_bf (32 rows per block, 256 blocks)
//  z=5: bias folds (single block (0,0)): bias_all[0,512)=bp, [512,1024)=bc,
//       [1024,1536)=bdelta, [1536,1568)=bdbc2[32:64)
// ---------------------------------------------------------------------------
__global__ __launch_bounds__(256) void prep_all(
    const float* __restrict__ x, const float* __restrict__ gamma, const float* __restrict__ beta,
    const float* __restrict__ Wp, const float* __restrict__ Wb,
    const float* __restrict__ Wdbc, const float* __restrict__ Wdt,
    const float* __restrict__ bp, const float* __restrict__ bb, const float* __restrict__ bdt,
    ushort* __restrict__ xn, ushort* __restrict__ Wp_bf, ushort* __restrict__ Wall,
    ushort* __restrict__ Wbt, ushort* __restrict__ Wdbct, ushort* __restrict__ Wdtt,
    float* __restrict__ bias_all)
{
    int z = blockIdx.z;
    if (z < 4) {
        __shared__ float t[32][33];
        int bx = blockIdx.x * 32, by = blockIdx.y * 32;
        int xx = threadIdx.x & 31, yy0 = threadIdx.x >> 5;
        const float* in; ushort* outT; int K, N;
        if (z == 0)      { in = Wp;   outT = Wall;  K = 512; N = 512; }
        else if (z == 1) { in = Wb;   outT = Wbt;   K = 512; N = 512; }
        else if (z == 2) { if (bx >= 64) return; in = Wdbc; outT = Wdbct; K = 512; N = 64; }
        else             { if (by >= 32) return; in = Wdt;  outT = Wdtt;  K = 32;  N = 512; }
        #pragma unroll
        for (int yy = yy0; yy < 32; yy += 8) {
            float v = in[(size_t)(by + yy) * N + bx + xx];
            t[yy][xx] = v;
            if (z == 0) Wp_bf[(size_t)(by + yy) * N + bx + xx] = f2bf(v);
        }
        __syncthreads();
        #pragma unroll
        for (int yy = yy0; yy < 32; yy += 8)
            outT[(size_t)(bx + yy) * K + by + xx] = f2bf(t[xx][yy]);
    } else if (z == 4) {
        int bid = blockIdx.y * 16 + blockIdx.x;       // 0..255
        int wv = threadIdx.x >> 6, lane = threadIdx.x & 63;
        const float4* g4 = (const float4*)gamma;
        const float4* b4 = (const float4*)beta;
        float4 g0 = g4[lane], g1 = g4[lane + 64];
        float4 be0 = b4[lane], be1 = b4[lane + 64];
        for (int rr = 0; rr < 8; ++rr) {
            int row = bid * 32 + wv * 8 + rr;
            const float4* xr = (const float4*)(x + (size_t)row * Ddim);
            float4 v0 = xr[lane];
            float4 v1 = xr[lane + 64];
            float s = v0.x + v0.y + v0.z + v0.w + v1.x + v1.y + v1.z + v1.w;
            float q = v0.x*v0.x + v0.y*v0.y + v0.z*v0.z + v0.w*v0.w
                    + v1.x*v1.x + v1.y*v1.y + v1.z*v1.z + v1.w*v1.w;
            #pragma unroll
            for (int m = 1; m <= 32; m <<= 1) { s += __shfl_xor(s, m); q += __shfl_xor(q, m); }
            float mu = s * (1.0f / Ddim);
            float var = q * (1.0f / Ddim) - mu * mu;
            float rs = rsqrtf(var + 1e-5f);
            ushort4 u0, u1;
            u0.x = f2bf((v0.x - mu) * rs * g0.x + be0.x);
            u0.y = f2bf((v0.y - mu) * rs * g0.y + be0.y);
            u0.z = f2bf((v0.z - mu) * rs * g0.z + be0.z);
            u0.w = f2bf((v0.w - mu) * rs * g0.w + be0.w);
            u1.x = f2bf((v1.x - mu) * rs * g1.x + be1.x);
            u1.y = f2bf((v1.y - mu) * rs * g1.y + be1.y);
            u1.z = f2bf((v1.z - mu) * rs * g1.z + be1.z);
            u1.w = f2bf((v1.w - mu) * rs * g1.w + be1.w);
            *(ushort4*)(xn + (size_t)row * Ddim + lane * 4) = u0;
            *(ushort4*)(xn + (size_t)row * Ddim + 256 + lane * 4) = u1;
        }
    } else {
        if (blockIdx.x != 0 || blockIdx.y != 0) return;
        __shared__ float sbc[512];
        __shared__ float sb2[64];
        int tid = threadIdx.x;
        #pragma unroll
        for (int rep = 0; rep < 2; ++rep) {
            int j = tid + rep * 256;
            float acc = bb[j];
            for (int k = 0; k < 512; ++k) acc = fmaf(bp[k], Wb[(size_t)k * 512 + j], acc);
            bias_all[j] = bp[j];
            bias_all[512 + j] = acc;
            sbc[j] = acc;
        }
        __syncthreads();
        if (tid < 64) {
            float acc = 0.f;
            for (int k = 0; k < 512; ++k) acc = fmaf(sbc[k], Wdbc[(size_t)k * 64 + tid], acc);
            sb2[tid] = acc;
            if (tid >= 32) bias_all[1536 + tid - 32] = acc;
        }
        __syncthreads();
        #pragma unroll
        for (int rep = 0; rep < 2; ++rep) {
            int j = tid + rep * 256;
            float acc = bdt[j];
            #pragma unroll
            for (int r = 0; r < 32; ++r) acc = fmaf(sb2[r], Wdt[(size_t)r * 512 + j], acc);
            bias_all[1024 + j] = acc;
        }
    }
}

// ---------------------------------------------------------------------------
// Fold GEMM 1: Wc = Wp @ Wb (512x512, K=512). 64x64 tiles, grid (8,8).
// Out: Wc_bf row-major + Wall rows [512,1024) = Wc^T.
// ---------------------------------------------------------------------------
__global__ __launch_bounds__(256) void gemm_wc64(
    const ushort* __restrict__ A, const ushort* __restrict__ Bt,
    ushort* __restrict__ Wc_bf, ushort* __restrict__ Wall)
{
    __shared__ __align__(16) ushort As[64 * 32];
    __shared__ __align__(16) ushort Bs[64 * 32];
    int tid = threadIdx.x, w = tid >> 6, lane = tid & 63;
    int bm = blockIdx.y * 64, bn = blockIdx.x * 64;
    int quad = lane >> 4, l16 = lane & 15;
    int srow = lane >> 2, schunk = (lane & 3) * 8;
    f32x4 acc[4] = {};
    for (int k0 = 0; k0 < 512; k0 += 32) {
        __syncthreads();
        GLD16(A  + (size_t)(bm + w * 16 + srow) * 512 + k0 + schunk, &As[(w * 16) * 32]);
        GLD16(Bt + (size_t)(bn + w * 16 + srow) * 512 + k0 + schunk, &Bs[(w * 16) * 32]);
        __syncthreads();
        bf16x8 bfr = *(const bf16x8*)(const void*)&Bs[(w * 16 + l16) * 32 + quad * 8];
        #pragma unroll
        for (int i = 0; i < 4; ++i) {
            bf16x8 af = *(const bf16x8*)(const void*)&As[(16 * i + l16) * 32 + quad * 8];
            acc[i] = __builtin_amdgcn_mfma_f32_16x16x32_bf16(af, bfr, acc[i], 0, 0, 0);
        }
    }
    #pragma unroll
    for (int i = 0; i < 4; ++i) {
        int row = bm + 16 * i + quad * 4;
        int col = bn + w * 16 + l16;
        #pragma unroll
        for (int r = 0; r < 4; ++r) {
            ushort v = f2bf(acc[i][r]);
            Wc_bf[(size_t)(row + r) * 512 + col] = v;
            Wall[(size_t)(512 + col) * 512 + row + r] = v;
        }
    }
}

// ---------------------------------------------------------------------------
// Fold GEMM 2: Wdbc2 = Wc @ Wdbc (512x64, K=512). grid (1,8).
// Out: Wdbc2_rm [512][64] + Wall rows [1536,1568) = Wdbc2[:,32:64]^T.
// ---------------------------------------------------------------------------
__global__ __launch_bounds__(256) void gemm_wdbc2_64(
    const ushort* __restrict__ A, const ushort* __restrict__ Bt,
    ushort* __restrict__ Wdbc2_rm, ushort* __restrict__ Wall)
{
    __shared__ __align__(16) ushort As[64 * 32];
    __shared__ __align__(16) ushort Bs[64 * 32];
    int tid = threadIdx.x, w = tid >> 6, lane = tid & 63;
    int bm = blockIdx.y * 64;
    int quad = lane >> 4, l16 = lane & 15;
    int srow = lane >> 2, schunk = (lane & 3) * 8;
    f32x4 acc[4] = {};
    for (int k0 = 0; k0 < 512; k0 += 32) {
        __syncthreads();
        GLD16(A  + (size_t)(bm + w * 16 + srow) * 512 + k0 + schunk, &As[(w * 16) * 32]);
        GLD16(Bt + (size_t)(w * 16 + srow) * 512 + k0 + schunk, &Bs[(w * 16) * 32]);
        __syncthreads();
        bf16x8 bfr = *(const bf16x8*)(const void*)&Bs[(w * 16 + l16) * 32 + quad * 8];
        #pragma unroll
        for (int i = 0; i < 4; ++i) {
            bf16x8 af = *(const bf16x8*)(const void*)&As[(16 * i + l16) * 32 + quad * 8];
            acc[i] = __builtin_amdgcn_mfma_f32_16x16x32_bf16(af, bfr, acc[i], 0, 0, 0);
        }
    }
    #pragma unroll
    for (int i = 0; i < 4; ++i) {
        int row = bm + 16 * i + quad * 4;
        int col = w * 16 + l16;
        #pragma unroll
        for (int r = 0; r < 4; ++r) {
            ushort v = f2bf(acc[i][r]);
            Wdbc2_rm[(size_t)(row + r) * 64 + col] = v;
            if (col >= 32)
                Wall[(size_t)(1536 + col - 32) * 512 + row + r] = v;
        }
    }
}

// ---------------------------------------------------------------------------
// Fold GEMM 3: Wdelta^T = Wdt^T @ Wdbc2[:,:32]^T  (512x512, K=32 one step).
// A=Wdtt [512][32], Bt=Wdbc2_rm (row d, cols 0..31, stride 64). grid (8,8).
// Out: Wall rows [1024,1536): Wall[(1024+j)*512+d].
// ---------------------------------------------------------------------------
__global__ __launch_bounds__(256) void gemm_wdelta_64(
    const ushort* __restrict__ A, const ushort* __restrict__ Bt,
    ushort* __restrict__ Wall)
{
    __shared__ __align__(16) ushort As[64 * 32];
    __shared__ __align__(16) ushort Bs[64 * 32];
    int tid = threadIdx.x, w = tid >> 6, lane = tid & 63;
    int bm = blockIdx.y * 64, bn = blockIdx.x * 64;
    int quad = lane >> 4, l16 = lane & 15;
    int srow = lane >> 2, schunk = (lane & 3) * 8;
    GLD16(A  + (size_t)(bm + w * 16 + srow) * 32 + schunk, &As[(w * 16) * 32]);
    GLD16(Bt + (size_t)(bn + w * 16 + srow) * 64 + schunk, &Bs[(w * 16) * 32]);
    __syncthreads();
    bf16x8 bfr = *(const bf16x8*)(const void*)&Bs[(w * 16 + l16) * 32 + quad * 8];
    f32x4 acc[4] = {};
    #pragma unroll
    for (int i = 0; i < 4; ++i) {
        bf16x8 af = *(const bf16x8*)(const void*)&As[(16 * i + l16) * 32 + quad * 8];
        acc[i] = __builtin_amdgcn_mfma_f32_16x16x32_bf16(af, bfr, acc[i], 0, 0, 0);
    }
    #pragma unroll
    for (int i = 0; i < 4; ++i) {
        int row = bm + 16 * i + quad * 4;
        int col = bn + w * 16 + l16;
        #pragma unroll
        for (int r = 0; r < 4; ++r)
            Wall[(size_t)(1024 + row + r) * 512 + col] = f2bf(acc[i][r]);
    }
}

// ---------------------------------------------------------------------------
// MEGA GEMM: [z1 | bwd | delta(softplus) | BC] = xn @ Wall + bias_all.
// BK=64, XOR-swizzled LDS chunks (conflict-free ds_read_b128), bf16 outputs
// (BC fp32). grid (64, 13): x = row-tile (same-A blocks land on one XCD),
// y = col-tile (0..11 = 128-wide, 12 = 32-wide BC).
// ---------------------------------------------------------------------------
__global__ __launch_bounds__(256) void gemm_mega(
    const ushort* __restrict__ A, const ushort* __restrict__ Wall,
    const float* __restrict__ bias_all,
    ushort* __restrict__ z1b, ushort* __restrict__ bwdb,
    ushort* __restrict__ deltab, float* __restrict__ BC)
{
    __shared__ __align__(16) ushort As[128 * 64];
    __shared__ __align__(16) ushort Bs[128 * 64];
    int tid = threadIdx.x, w = tid >> 6, lane = tid & 63;
    int bm = blockIdx.x * 128;
    int bt = blockIdx.y;
    int quad = lane >> 4, l16 = lane & 15;
    int srow8 = lane >> 3;
    int scolx = ((lane & 7) ^ (srow8 & 7)) * 8;          // swizzled global chunk
    int cof0 = (quad ^ (l16 & 7)) * 8;                   // ks=0 frag chunk
    int cof1 = ((4 + quad) ^ (l16 & 7)) * 8;             // ks=1 frag chunk

    if (bt < 12) {
        int bn = bt * 128;
        int wm = (w & 1) * 64, wn = (w >> 1) * 64;
        f32x4 acc[4][4] = {};
        for (int k0 = 0; k0 < 512; k0 += 64) {
            __syncthreads();
            #pragma unroll
            for (int s = 0; s < 4; ++s) {
                int r = w * 32 + s * 8;
                GLD16(A    + (size_t)(bm + r + srow8) * 512 + k0 + scolx, &As[r * 64]);
                GLD16(Wall + (size_t)(bn + r + srow8) * 512 + k0 + scolx, &Bs[r * 64]);
            }
            __syncthreads();
            #pragma unroll
            for (int ks = 0; ks < 2; ++ks) {
                int cof = ks ? cof1 : cof0;
                bf16x8 af[4], bfr[4];
                #pragma unroll
                for (int i = 0; i < 4; ++i)
                    af[i] = *(const bf16x8*)(const void*)&As[(wm + 16 * i + l16) * 64 + cof];
                #pragma unroll
                for (int j = 0; j < 4; ++j)
                    bfr[j] = *(const bf16x8*)(const void*)&Bs[(wn + 16 * j + l16) * 64 + cof];
                #pragma unroll
                for (int i = 0; i < 4; ++i)
                    #pragma unroll
                    for (int j = 0; j < 4; ++j)
                        acc[i][j] = __builtin_amdgcn_mfma_f32_16x16x32_bf16(af[i], bfr[j], acc[i][j], 0, 0, 0);
            }
        }
        int reg = bt >> 2;                     // 0=z1, 1=bwd, 2=delta
        ushort* obase = (reg == 0) ? z1b : (reg == 1) ? bwdb : deltab;
        #pragma unroll
        for (int i = 0; i < 4; ++i) {
            int row = bm + wm + 16 * i + quad * 4;
            #pragma unroll
            for (int j = 0; j < 4; ++j) {
                int gcol = bn + wn + 16 * j + l16;
                int lcol = gcol - (reg << 9);
                float bv = bias_all[gcol];
                #pragma unroll
                for (int r = 0; r < 4; ++r) {
                    float v = acc[i][j][r] + bv;
                    if (reg == 2) v = softplus_f(v);
                    obase[(size_t)(row + r) * 512 + lcol] = f2bf(v);
                }
            }
        }
    } else {
        int wm = w * 32;
        f32x4 acc[2][2] = {};
        for (int k0 = 0; k0 < 512; k0 += 64) {
            __syncthreads();
            #pragma unroll
            for (int s = 0; s < 4; ++s) {
                int r = w * 32 + s * 8;
                GLD16(A + (size_t)(bm + r + srow8) * 512 + k0 + scolx, &As[r * 64]);
            }
            {
                int r = w * 8;
                GLD16(Wall + (size_t)(1536 + r + srow8) * 512 + k0 + scolx, &Bs[r * 64]);
            }
            __syncthreads();
            #pragma unroll
            for (int ks = 0; ks < 2; ++ks) {
                int cof = ks ? cof1 : cof0;
                bf16x8 af[2], bfr[2];
                #pragma unroll
                for (int i = 0; i < 2; ++i)
                    af[i] = *(const bf16x8*)(const void*)&As[(wm + 16 * i + l16) * 64 + cof];
                #pragma unroll
                for (int j = 0; j < 2; ++j)
                    bfr[j] = *(const bf16x8*)(const void*)&Bs[(16 * j + l16) * 64 + cof];
                #pragma unroll
                for (int i = 0; i < 2; ++i)
                    #pragma unroll
                    for (int j = 0; j < 2; ++j)
                        acc[i][j] = __builtin_amdgcn_mfma_f32_16x16x32_bf16(af[i], bfr[j], acc[i][j], 0, 0, 0);
            }
        }
        #pragma unroll
        for (int i = 0; i < 2; ++i) {
            int row = bm + wm + 16 * i + quad * 4;
            #pragma unroll
            for (int j = 0; j < 2; ++j) {
                int col = 16 * j + l16;
                float bv = bias_all[1536 + col];
                #pragma unroll
                for (int r = 0; r < 4; ++r)
                    BC[(size_t)(row + r) * 32 + col] = acc[i][j][r] + bv;
            }
        }
    }
}

// ---------------------------------------------------------------------------
// Chunked parallel scan. BC [TOK][32]: cols 0..15 = B, 16..31 = C.
// ---------------------------------------------------------------------------
__global__ __launch_bounds__(256) void scan_pass1(
    const ushort* __restrict__ delta, const ushort* __restrict__ bwd,
    const float* __restrict__ BC, const float* __restrict__ A_log,
    float* __restrict__ hend, float* __restrict__ sdbuf)
{
    int d = (blockIdx.x << 8) + threadIdx.x;
    int c = blockIdx.y;
    int b = blockIdx.z;

    float A[16];
    {
        const float4* al = (const float4*)(A_log + (size_t)d * 16);
        #pragma unroll
        for (int i = 0; i < 4; ++i) {
            float4 v = al[i];
            A[4*i+0] = -__expf(v.x); A[4*i+1] = -__expf(v.y);
            A[4*i+2] = -__expf(v.z); A[4*i+3] = -__expf(v.w);
        }
    }
    float h[16];
    #pragma unroll
    for (int n = 0; n < 16; ++n) h[n] = 0.f;
    float sd = 0.f;

    size_t base = ((size_t)(b * Sdim + c * LCh)) * Ddim + d;
    const float* bcrow = BC + ((size_t)(b * Sdim + c * LCh)) * 32;

    #pragma unroll 2
    for (int i = 0; i < LCh; ++i) {
        float dlt = bf2f(delta[base + (size_t)i * Ddim]);
        float bw  = bf2f(bwd [base + (size_t)i * Ddim]);
        float4 B0 = *(const float4*)(bcrow + i * 32 + 0);
        float4 B1 = *(const float4*)(bcrow + i * 32 + 4);
        float4 B2 = *(const float4*)(bcrow + i * 32 + 8);
        float4 B3 = *(const float4*)(bcrow + i * 32 + 12);
        sd += dlt;
        float xb = dlt * bw;
        float Bv[16] = {B0.x,B0.y,B0.z,B0.w, B1.x,B1.y,B1.z,B1.w,
                        B2.x,B2.y,B2.z,B2.w, B3.x,B3.y,B3.z,B3.w};
        #pragma unroll
        for (int n = 0; n < 16; ++n)
            h[n] = fmaf(__expf(dlt * A[n]), h[n], xb * Bv[n]);
    }
    size_t cidx = ((((size_t)b * NCh + c) * Ddim) + d) * 16;
    float4* ho = (float4*)(hend + cidx);
    ho[0] = make_float4(h[0],  h[1],  h[2],  h[3]);
    ho[1] = make_float4(h[4],  h[5],  h[6],  h[7]);
    ho[2] = make_float4(h[8],  h[9],  h[10], h[11]);
    ho[3] = make_float4(h[12], h[13], h[14], h[15]);
    sdbuf[((size_t)b * NCh + c) * Ddim + d] = sd;
}

// carry combine, 8-wide batches (loads+exp independent of hin; only fma chains)
__global__ __launch_bounds__(256) void scan_pass2(
    float* __restrict__ hend, const float* __restrict__ sdbuf,
    const float* __restrict__ A_log)
{
    int gl = blockIdx.x * 256 + threadIdx.x;
    int b = gl >> 13;
    int r = gl & 8191;
    int d = r >> 4;
    float A = -__expf(A_log[r]);
    float hin = 0.f;
    for (int c0 = 0; c0 < NCh; c0 += 8) {
        float he[8], dec[8];
        #pragma unroll
        for (int u = 0; u < 8; ++u) {
            size_t idx = (((size_t)b * NCh + c0 + u) * Ddim) * 16 + r;
            he[u]  = hend[idx];
            dec[u] = __expf(A * sdbuf[((size_t)b * NCh + c0 + u) * Ddim + d]);
        }
        #pragma unroll
        for (int u = 0; u < 8; ++u) {
            size_t idx = (((size_t)b * NCh + c0 + u) * Ddim) * 16 + r;
            hend[idx] = hin;
            hin = fmaf(dec[u], hin, he[u]);
        }
    }
}

__global__ __launch_bounds__(256) void scan_pass3(
    const ushort* __restrict__ delta, const ushort* __restrict__ bwd,
    const float* __restrict__ BC, const ushort* __restrict__ z1,
    const float* __restrict__ x, const float* __restrict__ A_log,
    const float* __restrict__ D_ssm, const float* __restrict__ hin,
    float* __restrict__ out)
{
    int d = (blockIdx.x << 8) + threadIdx.x;
    int c = blockIdx.y;
    int b = blockIdx.z;

    float A[16];
    {
        const float4* al = (const float4*)(A_log + (size_t)d * 16);
        #pragma unroll
        for (int i = 0; i < 4; ++i) {
            float4 v = al[i];
            A[4*i+0] = -__expf(v.x); A[4*i+1] = -__expf(v.y);
            A[4*i+2] = -__expf(v.z); A[4*i+3] = -__expf(v.w);
        }
    }
    float h[16];
    {
        size_t cidx = ((((size_t)b * NCh + c) * Ddim) + d) * 16;
        const float4* hi = (const float4*)(hin + cidx);
        float4 h0 = hi[0], h1 = hi[1], h2 = hi[2], h3 = hi[3];
        h[0]=h0.x; h[1]=h0.y; h[2]=h0.z; h[3]=h0.w;
        h[4]=h1.x; h[5]=h1.y; h[6]=h1.z; h[7]=h1.w;
        h[8]=h2.x; h[9]=h2.y; h[10]=h2.z; h[11]=h2.w;
        h[12]=h3.x; h[13]=h3.y; h[14]=h3.z; h[15]=h3.w;
    }
    float Dd = D_ssm[d];

    size_t base = ((size_t)(b * Sdim + c * LCh)) * Ddim + d;
    const float* bcrow = BC + ((size_t)(b * Sdim + c * LCh)) * 32;

    #pragma unroll 2
    for (int i = 0; i < LCh; ++i) {
        float dlt = bf2f(delta[base + (size_t)i * Ddim]);
        float bw  = bf2f(bwd [base + (size_t)i * Ddim]);
        float z1v = bf2f(z1  [base + (size_t)i * Ddim]);
        float xv  = x[base + (size_t)i * Ddim];
        float4 B0 = *(const float4*)(bcrow + i * 32 + 0);
        float4 B1 = *(const float4*)(bcrow + i * 32 + 4);
        float4 B2 = *(const float4*)(bcrow + i * 32 + 8);
        float4 B3 = *(const float4*)(bcrow + i * 32 + 12);
        float4 C0 = *(const float4*)(bcrow + i * 32 + 16);
        float4 C1 = *(const float4*)(bcrow + i * 32 + 20);
        float4 C2 = *(const float4*)(bcrow + i * 32 + 24);
        float4 C3 = *(const float4*)(bcrow + i * 32 + 28);
        float Bv[16] = {B0.x,B0.y,B0.z,B0.w, B1.x,B1.y,B1.z,B1.w,
                        B2.x,B2.y,B2.z,B2.w, B3.x,B3.y,B3.z,B3.w};
        float Cv[16] = {C0.x,C0.y,C0.z,C0.w, C1.x,C1.y,C1.z,C1.w,
                        C2.x,C2.y,C2.z,C2.w, C3.x,C3.y,C3.z,C3.w};
        float xb = dlt * bw;
        float y  = Dd * bw;
        #pragma unroll
        for (int n = 0; n < 16; ++n) {
            h[n] = fmaf(__expf(dlt * A[n]), h[n], xb * Bv[n]);
            y = fmaf(h[n], Cv[n], y);
        }
        float silu = z1v / (1.f + __expf(-z1v));
        out[base + (size_t)i * Ddim] = fmaf(z1v + y, silu, xv);
    }
}

// ---------------------------------------------------------------------------
extern "C" void kernel_launch(void* const* d_in, const int* in_sizes, int n_in,
                              void* d_out, int out_size, void* d_ws, size_t ws_size,
                              hipStream_t stream) {
    const float* x      = (const float*)d_in[0];
    const float* gamma  = (const float*)d_in[1];
    const float* beta   = (const float*)d_in[2];
    const float* W_proj = (const float*)d_in[3];
    const float* b_proj = (const float*)d_in[4];
    // d_in[5]=W_fwd, d_in[6]=b_fwd dead in reference (x1_ssm unused)
    const float* W_bwd  = (const float*)d_in[7];
    const float* b_bwd  = (const float*)d_in[8];
    const float* W_dbc  = (const float*)d_in[9];
    const float* W_dt   = (const float*)d_in[10];
    const float* b_dt   = (const float*)d_in[11];
    const float* A_log  = (const float*)d_in[12];
    const float* D_ssm  = (const float*)d_in[13];
    float* out = (float*)d_out;

    char* p = (char*)d_ws;
    ushort* xn_bf    = (ushort*)p;                        // 8 MB   [0,8M)
    ushort* z1_bf    = (ushort*)(p + (8ull  << 20));      // 8 MB
    ushort* bwd_bf   = (ushort*)(p + (16ull << 20));      // 8 MB
    ushort* delta_bf = (ushort*)(p + (24ull << 20));      // 8 MB
    float*  BC       = (float*)(p + (32ull << 20));       // 1 MB
    float*  hend     = (float*)(p + (33ull << 20));       // 8 MB
    float*  sdbuf    = (float*)(p + (41ull << 20));       // 512 KB
    ushort* Wall     = (ushort*)(p + (42ull << 20));      // 1.53 MB (1568x512 bf16)
    ushort* Wp_bf    = (ushort*)(p + (44ull << 20));      // 512 KB
    ushort* Wbt      = Wp_bf + (size_t)512 * 512;         // 512 KB
    ushort* Wc_bf    = Wbt   + (size_t)512 * 512;         // 512 KB
    ushort* Wdbct    = Wc_bf + (size_t)512 * 512;         // 64 KB
    ushort* Wdtt     = Wdbct + (size_t)64 * 512;          // 32 KB
    ushort* Wdbc2_rm = Wdtt  + (size_t)512 * 32;          // 64 KB
    float*  bias_all = (float*)(Wdbc2_rm + (size_t)512 * 64);  // 6.3 KB

    // 1. prep: transposes + LayerNorm + bias folds (one dispatch)
    prep_all<<<dim3(16, 16, 6), dim3(256), 0, stream>>>(
        x, gamma, beta, W_proj, W_bwd, W_dbc, W_dt, b_proj, b_bwd, b_dt,
        xn_bf, Wp_bf, Wall, Wbt, Wdbct, Wdtt, bias_all);
    // 2-4. weight folds
    gemm_wc64<<<dim3(8, 8), dim3(256), 0, stream>>>(Wp_bf, Wbt, Wc_bf, Wall);
    gemm_wdbc2_64<<<dim3(1, 8), dim3(256), 0, stream>>>(Wc_bf, Wdbct, Wdbc2_rm, Wall);
    gemm_wdelta_64<<<dim3(8, 8), dim3(256), 0, stream>>>(Wdtt, Wdbc2_rm, Wall);
    // 5. mega GEMM
    gemm_mega<<<dim3(64, 13), dim3(256), 0, stream>>>(
        xn_bf, Wall, bias_all, z1_bf, bwd_bf, delta_bf, BC);
    // 6-8. chunked scan
    scan_pass1<<<dim3(2, NCh, Bb), dim3(256), 0, stream>>>(delta_bf, bwd_bf, BC, A_log, hend, sdbuf);
    scan_pass2<<<dim3(Bb * Ddim * Nn16 / 256), dim3(256), 0, stream>>>(hend, sdbuf, A_log);
    scan_pass3<<<dim3(2, NCh, Bb), dim3(256), 0, stream>>>(delta_bf, bwd_bf, BC, z1_bf, x, A_log, D_ssm, hend, out);
}

// Round 8
// 206.020 us; speedup vs baseline: 1.2361x; 1.2361x over previous
//
#include <hip/hip_runtime.h>
#include <hip/hip_bf16.h>
#include <math.h>

// Problem dims
#define Bb 4
#define Sdim 2048
#define Ddim 512
#define Nn16 16
#define TOK 8192          // Bb*Sdim
#define NCh 64            // chunks along S
#define LCh 32            // steps per chunk

using bf16x8 = __attribute__((ext_vector_type(8))) __bf16;
using f32x4  = __attribute__((ext_vector_type(4))) float;

__device__ __forceinline__ unsigned short f2bf(float f) {
    unsigned int u = __float_as_uint(f);
    u += 0x7fffu + ((u >> 16) & 1u);
    return (unsigned short)(u >> 16);
}
__device__ __forceinline__ float bf2f(unsigned short h) {
    return __uint_as_float(((unsigned int)h) << 16);
}

// async global->LDS, 16B/lane; LDS base wave-uniform
#define GLD16(g, l) __builtin_amdgcn_global_load_lds( \
    (const __attribute__((address_space(1))) void*)(g), \
    (__attribute__((address_space(3))) void*)(l), 16, 0, 0)

__device__ __forceinline__ float softplus_f(float v) {
    return v > 20.f ? v : log1pf(__expf(v));
}

// ---------------------------------------------------------------------------
// PREP: one dispatch, 816 blocks x 256 threads.
//  blk [0,256):   Wp [512][512] -> Wpt [N][K] bf16
//  blk [256,512): Wb -> Wbt
//  blk [512,544): Wdbc [512][64] -> Wdbct [64][512]
//  blk [544,560): Wdt [32][512] -> WdtT [512][32]
//  blk [560,816): LayerNorm -> xn bf16 (32 rows per block)
// ---------------------------------------------------------------------------
__global__ __launch_bounds__(256) void prep_all(
    const float* __restrict__ x, const float* __restrict__ gamma, const float* __restrict__ beta,
    const float* __restrict__ Wp, const float* __restrict__ Wb,
    const float* __restrict__ Wdbc, const float* __restrict__ Wdt,
    ushort* __restrict__ xn, ushort* __restrict__ Wpt, ushort* __restrict__ Wbt,
    ushort* __restrict__ Wdbct, ushort* __restrict__ WdtT)
{
    int blk = blockIdx.x;
    int tid = threadIdx.x;
    if (blk < 560) {
        __shared__ float tb[32 * 33];
        int xx = tid & 31, yy0 = tid >> 5;
        const float* in; ushort* outT; int K, N, bx, by;
        if (blk < 256)      { in = Wp;   outT = Wpt;   K = 512; N = 512; bx = (blk & 15) * 32; by = (blk >> 4) * 32; }
        else if (blk < 512) { int t = blk - 256; in = Wb; outT = Wbt; K = 512; N = 512; bx = (t & 15) * 32; by = (t >> 4) * 32; }
        else if (blk < 544) { int t = blk - 512; in = Wdbc; outT = Wdbct; K = 512; N = 64; bx = (t & 1) * 32; by = (t >> 1) * 32; }
        else                { int t = blk - 544; in = Wdt; outT = WdtT; K = 32; N = 512; bx = t * 32; by = 0; }
        #pragma unroll
        for (int yy = yy0; yy < 32; yy += 8)
            tb[yy * 33 + xx] = in[(size_t)(by + yy) * N + bx + xx];
        __syncthreads();
        #pragma unroll
        for (int yy = yy0; yy < 32; yy += 8)
            outT[(size_t)(bx + yy) * K + by + xx] = f2bf(tb[xx * 33 + yy]);
    } else {
        int bid = blk - 560;                 // 0..255
        int w = tid >> 6, lane = tid & 63;
        const float4* g4 = (const float4*)gamma;
        const float4* b4 = (const float4*)beta;
        float4 g0 = g4[lane], g1 = g4[lane + 64];
        float4 be0 = b4[lane], be1 = b4[lane + 64];
        for (int rr = 0; rr < 8; ++rr) {
            int row = bid * 32 + w * 8 + rr;
            const float4* xr = (const float4*)(x + (size_t)row * Ddim);
            float4 v0 = xr[lane];
            float4 v1 = xr[lane + 64];
            float s = v0.x + v0.y + v0.z + v0.w + v1.x + v1.y + v1.z + v1.w;
            float q = v0.x*v0.x + v0.y*v0.y + v0.z*v0.z + v0.w*v0.w
                    + v1.x*v1.x + v1.y*v1.y + v1.z*v1.z + v1.w*v1.w;
            #pragma unroll
            for (int m = 1; m <= 32; m <<= 1) { s += __shfl_xor(s, m); q += __shfl_xor(q, m); }
            float mu = s * (1.0f / Ddim);
            float var = q * (1.0f / Ddim) - mu * mu;
            float rs = rsqrtf(var + 1e-5f);
            ushort4 u0, u1;
            u0.x = f2bf((v0.x - mu) * rs * g0.x + be0.x);
            u0.y = f2bf((v0.y - mu) * rs * g0.y + be0.y);
            u0.z = f2bf((v0.z - mu) * rs * g0.z + be0.z);
            u0.w = f2bf((v0.w - mu) * rs * g0.w + be0.w);
            u1.x = f2bf((v1.x - mu) * rs * g1.x + be1.x);
            u1.y = f2bf((v1.y - mu) * rs * g1.y + be1.y);
            u1.z = f2bf((v1.z - mu) * rs * g1.z + be1.z);
            u1.w = f2bf((v1.w - mu) * rs * g1.w + be1.w);
            *(ushort4*)(xn + (size_t)row * Ddim + lane * 4) = u0;
            *(ushort4*)(xn + (size_t)row * Ddim + 256 + lane * 4) = u1;
        }
    }
}

// ---------------------------------------------------------------------------
// bf16 MFMA GEMM, 128x128 tile, BK=32 (round-4 proven structure).
// C = bf16(A @ Bt^T + bias). grid (N/128, M/128).
// ---------------------------------------------------------------------------
__global__ __launch_bounds__(256) void gemm_bf(
    const ushort* __restrict__ A,  // [M][512] bf16
    const ushort* __restrict__ Bt, // [512][512] bf16 (W^T)
    const float* __restrict__ bias,
    ushort* __restrict__ Cb)
{
    __shared__ __align__(16) ushort As[128 * 32];
    __shared__ __align__(16) ushort Bs[128 * 32];
    int tid = threadIdx.x, w = tid >> 6, lane = tid & 63;
    int bm = blockIdx.y * 128, bn = blockIdx.x * 128;
    int wm = (w & 1) * 64, wn = (w >> 1) * 64;
    int quad = lane >> 4, l16 = lane & 15;
    int srow = lane >> 2, schunk = (lane & 3) * 8;
    f32x4 acc[4][4] = {};

    for (int k0 = 0; k0 < 512; k0 += 32) {
        __syncthreads();
        #pragma unroll
        for (int s = 0; s < 2; ++s) {
            int r = w * 32 + s * 16;
            GLD16(A  + (size_t)(bm + r + srow) * 512 + k0 + schunk, &As[r * 32]);
            GLD16(Bt + (size_t)(bn + r + srow) * 512 + k0 + schunk, &Bs[r * 32]);
        }
        __syncthreads();
        bf16x8 af[4], bfr[4];
        #pragma unroll
        for (int i = 0; i < 4; ++i)
            af[i] = *(const bf16x8*)(const void*)&As[(wm + 16 * i + l16) * 32 + quad * 8];
        #pragma unroll
        for (int j = 0; j < 4; ++j)
            bfr[j] = *(const bf16x8*)(const void*)&Bs[(wn + 16 * j + l16) * 32 + quad * 8];
        #pragma unroll
        for (int i = 0; i < 4; ++i)
            #pragma unroll
            for (int j = 0; j < 4; ++j)
                acc[i][j] = __builtin_amdgcn_mfma_f32_16x16x32_bf16(af[i], bfr[j], acc[i][j], 0, 0, 0);
    }
    #pragma unroll
    for (int i = 0; i < 4; ++i) {
        int row = bm + wm + 16 * i + quad * 4;
        #pragma unroll
        for (int j = 0; j < 4; ++j) {
            int col = bn + wn + 16 * j + l16;
            float bv = bias[col];
            #pragma unroll
            for (int r = 0; r < 4; ++r)
                Cb[(size_t)(row + r) * 512 + col] = f2bf(acc[i][j][r] + bv);
        }
    }
}

// ---------------------------------------------------------------------------
// dbc GEMM: [dbc_bf (cols 0..31) | BC fp32 (cols 32..63)] = bwd @ Wdbc.
// 128x64 tile, BK=32 (round-4 proven structure). grid (1,64).
// ---------------------------------------------------------------------------
__global__ __launch_bounds__(256) void gemm_dbc(
    const ushort* __restrict__ A,  // bwd [8192][512]
    const ushort* __restrict__ Bt, // Wdbct [64][512]
    ushort* __restrict__ dbc,      // [8192][32] bf16
    float* __restrict__ BC)        // [8192][32] fp32
{
    __shared__ __align__(16) ushort As[128 * 32];
    __shared__ __align__(16) ushort Bs[64 * 32];
    int tid = threadIdx.x, w = tid >> 6, lane = tid & 63;
    int bm = blockIdx.y * 128;
    int wm = w * 32;
    int quad = lane >> 4, l16 = lane & 15;
    int srow = lane >> 2, schunk = (lane & 3) * 8;
    f32x4 acc[2][4] = {};

    for (int k0 = 0; k0 < 512; k0 += 32) {
        __syncthreads();
        #pragma unroll
        for (int s = 0; s < 2; ++s) {
            int r = w * 32 + s * 16;
            GLD16(A + (size_t)(bm + r + srow) * 512 + k0 + schunk, &As[r * 32]);
        }
        {
            int r = w * 16;
            GLD16(Bt + (size_t)(r + srow) * 512 + k0 + schunk, &Bs[r * 32]);
        }
        __syncthreads();
        bf16x8 af[2], bfr[4];
        #pragma unroll
        for (int i = 0; i < 2; ++i)
            af[i] = *(const bf16x8*)(const void*)&As[(wm + 16 * i + l16) * 32 + quad * 8];
        #pragma unroll
        for (int j = 0; j < 4; ++j)
            bfr[j] = *(const bf16x8*)(const void*)&Bs[(16 * j + l16) * 32 + quad * 8];
        #pragma unroll
        for (int i = 0; i < 2; ++i)
            #pragma unroll
            for (int j = 0; j < 4; ++j)
                acc[i][j] = __builtin_amdgcn_mfma_f32_16x16x32_bf16(af[i], bfr[j], acc[i][j], 0, 0, 0);
    }
    #pragma unroll
    for (int i = 0; i < 2; ++i) {
        int row = bm + wm + 16 * i + quad * 4;
        #pragma unroll
        for (int j = 0; j < 4; ++j) {
            int col = 16 * j + l16;
            #pragma unroll
            for (int r = 0; r < 4; ++r) {
                float v = acc[i][j][r];
                if (col < 32) dbc[(size_t)(row + r) * 32 + col] = f2bf(v);
                else          BC [(size_t)(row + r) * 32 + col - 32] = v;
            }
        }
    }
}

// ---------------------------------------------------------------------------
// delta = softplus(dbc @ Wdt + b_dt): K=32 single MFMA step (round-4 proven).
// A = dbc_bf [8192][32], Bt = WdtT [512][32]. grid (4,64). bf16 out.
// ---------------------------------------------------------------------------
__global__ __launch_bounds__(256) void gemm_delta(
    const ushort* __restrict__ A, const ushort* __restrict__ Bt,
    const float* __restrict__ b_dt, ushort* __restrict__ delta)
{
    __shared__ __align__(16) ushort As[128 * 32];
    __shared__ __align__(16) ushort Bs[128 * 32];
    int tid = threadIdx.x, w = tid >> 6, lane = tid & 63;
    int bm = blockIdx.y * 128, bn = blockIdx.x * 128;
    int wm = (w & 1) * 64, wn = (w >> 1) * 64;
    int quad = lane >> 4, l16 = lane & 15;
    int srow16 = lane >> 2, sch = (lane & 3) * 8;   // 16 rows x 4 chunks of 8

    #pragma unroll
    for (int s = 0; s < 2; ++s) {
        int r = w * 32 + s * 16;
        GLD16(A  + (size_t)(bm + r + srow16) * 32 + sch, &As[r * 32]);
        GLD16(Bt + (size_t)(bn + r + srow16) * 32 + sch, &Bs[r * 32]);
    }
    __syncthreads();
    bf16x8 af[4], bfr[4];
    #pragma unroll
    for (int i = 0; i < 4; ++i)
        af[i] = *(const bf16x8*)(const void*)&As[(wm + 16 * i + l16) * 32 + quad * 8];
    #pragma unroll
    for (int j = 0; j < 4; ++j)
        bfr[j] = *(const bf16x8*)(const void*)&Bs[(wn + 16 * j + l16) * 32 + quad * 8];
    f32x4 acc[4][4] = {};
    #pragma unroll
    for (int i = 0; i < 4; ++i)
        #pragma unroll
        for (int j = 0; j < 4; ++j)
            acc[i][j] = __builtin_amdgcn_mfma_f32_16x16x32_bf16(af[i], bfr[j], acc[i][j], 0, 0, 0);
    #pragma unroll
    for (int i = 0; i < 4; ++i) {
        int row = bm + wm + 16 * i + quad * 4;
        #pragma unroll
        for (int j = 0; j < 4; ++j) {
            int col = bn + wn + 16 * j + l16;
            float bv = b_dt[col];
            #pragma unroll
            for (int r = 0; r < 4; ++r)
                delta[(size_t)(row + r) * 512 + col] = f2bf(softplus_f(acc[i][j][r] + bv));
        }
    }
}

// ---------------------------------------------------------------------------
// Chunked parallel scan (round-6 proven, bf16 inputs).
// BC [TOK][32]: cols 0..15 = B, 16..31 = C.
// ---------------------------------------------------------------------------
__global__ __launch_bounds__(256) void scan_pass1(
    const ushort* __restrict__ delta, const ushort* __restrict__ bwd,
    const float* __restrict__ BC, const float* __restrict__ A_log,
    float* __restrict__ hend, float* __restrict__ sdbuf)
{
    int d = (blockIdx.x << 8) + threadIdx.x;
    int c = blockIdx.y;
    int b = blockIdx.z;

    float A[16];
    {
        const float4* al = (const float4*)(A_log + (size_t)d * 16);
        #pragma unroll
        for (int i = 0; i < 4; ++i) {
            float4 v = al[i];
            A[4*i+0] = -__expf(v.x); A[4*i+1] = -__expf(v.y);
            A[4*i+2] = -__expf(v.z); A[4*i+3] = -__expf(v.w);
        }
    }
    float h[16];
    #pragma unroll
    for (int n = 0; n < 16; ++n) h[n] = 0.f;
    float sd = 0.f;

    size_t base = ((size_t)(b * Sdim + c * LCh)) * Ddim + d;
    const float* bcrow = BC + ((size_t)(b * Sdim + c * LCh)) * 32;

    #pragma unroll 2
    for (int i = 0; i < LCh; ++i) {
        float dlt = bf2f(delta[base + (size_t)i * Ddim]);
        float bw  = bf2f(bwd [base + (size_t)i * Ddim]);
        float4 B0 = *(const float4*)(bcrow + i * 32 + 0);
        float4 B1 = *(const float4*)(bcrow + i * 32 + 4);
        float4 B2 = *(const float4*)(bcrow + i * 32 + 8);
        float4 B3 = *(const float4*)(bcrow + i * 32 + 12);
        sd += dlt;
        float xb = dlt * bw;
        float Bv[16] = {B0.x,B0.y,B0.z,B0.w, B1.x,B1.y,B1.z,B1.w,
                        B2.x,B2.y,B2.z,B2.w, B3.x,B3.y,B3.z,B3.w};
        #pragma unroll
        for (int n = 0; n < 16; ++n)
            h[n] = fmaf(__expf(dlt * A[n]), h[n], xb * Bv[n]);
    }
    size_t cidx = ((((size_t)b * NCh + c) * Ddim) + d) * 16;
    float4* ho = (float4*)(hend + cidx);
    ho[0] = make_float4(h[0],  h[1],  h[2],  h[3]);
    ho[1] = make_float4(h[4],  h[5],  h[6],  h[7]);
    ho[2] = make_float4(h[8],  h[9],  h[10], h[11]);
    ho[3] = make_float4(h[12], h[13], h[14], h[15]);
    sdbuf[((size_t)b * NCh + c) * Ddim + d] = sd;
}

__global__ __launch_bounds__(256) void scan_pass2(
    float* __restrict__ hend, const float* __restrict__ sdbuf,
    const float* __restrict__ A_log)
{
    int gl = blockIdx.x * 256 + threadIdx.x;
    int b = gl >> 13;
    int r = gl & 8191;
    int d = r >> 4;
    float A = -__expf(A_log[r]);
    float hin = 0.f;
    for (int c0 = 0; c0 < NCh; c0 += 8) {
        float he[8], dec[8];
        #pragma unroll
        for (int u = 0; u < 8; ++u) {
            size_t idx = (((size_t)b * NCh + c0 + u) * Ddim) * 16 + r;
            he[u]  = hend[idx];
            dec[u] = __expf(A * sdbuf[((size_t)b * NCh + c0 + u) * Ddim + d]);
        }
        #pragma unroll
        for (int u = 0; u < 8; ++u) {
            size_t idx = (((size_t)b * NCh + c0 + u) * Ddim) * 16 + r;
            hend[idx] = hin;
            hin = fmaf(dec[u], hin, he[u]);
        }
    }
}

__global__ __launch_bounds__(256) void scan_pass3(
    const ushort* __restrict__ delta, const ushort* __restrict__ bwd,
    const float* __restrict__ BC, const ushort* __restrict__ z1,
    const float* __restrict__ x, const float* __restrict__ A_log,
    const float* __restrict__ D_ssm, const float* __restrict__ hin,
    float* __restrict__ out)
{
    int d = (blockIdx.x << 8) + threadIdx.x;
    int c = blockIdx.y;
    int b = blockIdx.z;

    float A[16];
    {
        const float4* al = (const float4*)(A_log + (size_t)d * 16);
        #pragma unroll
        for (int i = 0; i < 4; ++i) {
            float4 v = al[i];
            A[4*i+0] = -__expf(v.x); A[4*i+1] = -__expf(v.y);
            A[4*i+2] = -__expf(v.z); A[4*i+3] = -__expf(v.w);
        }
    }
    float h[16];
    {
        size_t cidx = ((((size_t)b * NCh + c) * Ddim) + d) * 16;
        const float4* hi = (const float4*)(hin + cidx);
        float4 h0 = hi[0], h1 = hi[1], h2 = hi[2], h3 = hi[3];
        h[0]=h0.x; h[1]=h0.y; h[2]=h0.z; h[3]=h0.w;
        h[4]=h1.x; h[5]=h1.y; h[6]=h1.z; h[7]=h1.w;
        h[8]=h2.x; h[9]=h2.y; h[10]=h2.z; h[11]=h2.w;
        h[12]=h3.x; h[13]=h3.y; h[14]=h3.z; h[15]=h3.w;
    }
    float Dd = D_ssm[d];

    size_t base = ((size_t)(b * Sdim + c * LCh)) * Ddim + d;
    const float* bcrow = BC + ((size_t)(b * Sdim + c * LCh)) * 32;

    #pragma unroll 2
    for (int i = 0; i < LCh; ++i) {
        float dlt = bf2f(delta[base + (size_t)i * Ddim]);
        float bw  = bf2f(bwd [base + (size_t)i * Ddim]);
        float z1v = bf2f(z1  [base + (size_t)i * Ddim]);
        float xv  = x[base + (size_t)i * Ddim];
        float4 B0 = *(const float4*)(bcrow + i * 32 + 0);
        float4 B1 = *(const float4*)(bcrow + i * 32 + 4);
        float4 B2 = *(const float4*)(bcrow + i * 32 + 8);
        float4 B3 = *(const float4*)(bcrow + i * 32 + 12);
        float4 C0 = *(const float4*)(bcrow + i * 32 + 16);
        float4 C1 = *(const float4*)(bcrow + i * 32 + 20);
        float4 C2 = *(const float4*)(bcrow + i * 32 + 24);
        float4 C3 = *(const float4*)(bcrow + i * 32 + 28);
        float Bv[16] = {B0.x,B0.y,B0.z,B0.w, B1.x,B1.y,B1.z,B1.w,
                        B2.x,B2.y,B2.z,B2.w, B3.x,B3.y,B3.z,B3.w};
        float Cv[16] = {C0.x,C0.y,C0.z,C0.w, C1.x,C1.y,C1.z,C1.w,
                        C2.x,C2.y,C2.z,C2.w, C3.x,C3.y,C3.z,C3.w};
        float xb = dlt * bw;
        float y  = Dd * bw;
        #pragma unroll
        for (int n = 0; n < 16; ++n) {
            h[n] = fmaf(__expf(dlt * A[n]), h[n], xb * Bv[n]);
            y = fmaf(h[n], Cv[n], y);
        }
        float silu = z1v / (1.f + __expf(-z1v));
        out[base + (size_t)i * Ddim] = fmaf(z1v + y, silu, xv);
    }
}

// ---------------------------------------------------------------------------
extern "C" void kernel_launch(void* const* d_in, const int* in_sizes, int n_in,
                              void* d_out, int out_size, void* d_ws, size_t ws_size,
                              hipStream_t stream) {
    const float* x      = (const float*)d_in[0];
    const float* gamma  = (const float*)d_in[1];
    const float* beta   = (const float*)d_in[2];
    const float* W_proj = (const float*)d_in[3];
    const float* b_proj = (const float*)d_in[4];
    // d_in[5]=W_fwd, d_in[6]=b_fwd dead in reference (x1_ssm unused)
    const float* W_bwd  = (const float*)d_in[7];
    const float* b_bwd  = (const float*)d_in[8];
    const float* W_dbc  = (const float*)d_in[9];
    const float* W_dt   = (const float*)d_in[10];
    const float* b_dt   = (const float*)d_in[11];
    const float* A_log  = (const float*)d_in[12];
    const float* D_ssm  = (const float*)d_in[13];
    float* out = (float*)d_out;

    char* p = (char*)d_ws;
    ushort* xn_bf    = (ushort*)p;                        // 8 MB  [0,8M)
    ushort* z1_bf    = (ushort*)(p + (8ull  << 20));      // 8 MB
    ushort* bwd_bf   = (ushort*)(p + (16ull << 20));      // 8 MB
    ushort* delta_bf = (ushort*)(p + (24ull << 20));      // 8 MB
    ushort* dbc_bf   = (ushort*)(p + (32ull << 20));      // 0.5 MB [8192][32]
    float*  BC       = (float*) (p + (33ull << 20));      // 1 MB   [8192][32]
    float*  hend     = (float*) (p + (34ull << 20));      // 8 MB
    float*  sdbuf    = (float*) (p + (42ull << 20));      // 0.5 MB
    ushort* Wpt      = (ushort*)(p + (43ull << 20));      // 0.5 MB
    ushort* Wbt      = Wpt   + (size_t)512 * 512;         // 0.5 MB
    ushort* Wdbct    = Wbt   + (size_t)512 * 512;         // 64 KB  [64][512]
    ushort* WdtT     = Wdbct + (size_t)64 * 512;          // 32 KB  [512][32]

    // 1. prep: transposes + LayerNorm (one dispatch)
    prep_all<<<dim3(816), dim3(256), 0, stream>>>(
        x, gamma, beta, W_proj, W_bwd, W_dbc, W_dt, xn_bf, Wpt, Wbt, Wdbct, WdtT);
    // 2. z1 = xn @ Wp + bp
    gemm_bf<<<dim3(4, 64), dim3(256), 0, stream>>>(xn_bf, Wpt, b_proj, z1_bf);
    // 3. bwd = z1 @ Wb + bb
    gemm_bf<<<dim3(4, 64), dim3(256), 0, stream>>>(z1_bf, Wbt, b_bwd, bwd_bf);
    // 4. [dbc | BC] = bwd @ Wdbc
    gemm_dbc<<<dim3(1, 64), dim3(256), 0, stream>>>(bwd_bf, Wdbct, dbc_bf, BC);
    // 5. delta = softplus(dbc @ Wdt + b_dt)
    gemm_delta<<<dim3(4, 64), dim3(256), 0, stream>>>(dbc_bf, WdtT, b_dt, delta_bf);
    // 6-8. chunked scan
    scan_pass1<<<dim3(2, NCh, Bb), dim3(256), 0, stream>>>(delta_bf, bwd_bf, BC, A_log, hend, sdbuf);
    scan_pass2<<<dim3(128), dim3(256), 0, stream>>>(hend, sdbuf, A_log);
    scan_pass3<<<dim3(2, NCh, Bb), dim3(256), 0, stream>>>(delta_bf, bwd_bf, BC, z1_bf, x, A_log, D_ssm, hend, out);
}

// Round 9
// 191.945 us; speedup vs baseline: 1.3268x; 1.0733x over previous
//
#include <hip/hip_runtime.h>
#include <hip/hip_bf16.h>
#include <math.h>

// Problem dims
#define Bb 4
#define Sdim 2048
#define Ddim 512
#define Nn16 16
#define TOK 8192          // Bb*Sdim
#define NCh 64            // chunks along S
#define LCh 32            // steps per chunk

using bf16x8 = __attribute__((ext_vector_type(8))) __bf16;
using f32x4  = __attribute__((ext_vector_type(4))) float;

__device__ __forceinline__ unsigned short f2bf(float f) {
    unsigned int u = __float_as_uint(f);
    u += 0x7fffu + ((u >> 16) & 1u);
    return (unsigned short)(u >> 16);
}
__device__ __forceinline__ float bf2f(unsigned short h) {
    return __uint_as_float(((unsigned int)h) << 16);
}

// async global->LDS, 16B/lane; LDS base wave-uniform
#define GLD16(g, l) __builtin_amdgcn_global_load_lds( \
    (const __attribute__((address_space(1))) void*)(g), \
    (__attribute__((address_space(3))) void*)(l), 16, 0, 0)

__device__ __forceinline__ float softplus_f(float v) {
    return v > 20.f ? v : log1pf(__expf(v));
}

// ---------------------------------------------------------------------------
// PREP: one dispatch, 816 blocks x 256 threads (round-8 proven).
//  blk [0,256):   Wp [512][512] -> Wpt [N][K] bf16
//  blk [256,512): Wb -> Wbt
//  blk [512,544): Wdbc [512][64] -> Wdbct [64][512]
//  blk [544,560): Wdt [32][512] -> WdtT [512][32]
//  blk [560,816): LayerNorm -> xn bf16 (32 rows per block)
// ---------------------------------------------------------------------------
__global__ __launch_bounds__(256) void prep_all(
    const float* __restrict__ x, const float* __restrict__ gamma, const float* __restrict__ beta,
    const float* __restrict__ Wp, const float* __restrict__ Wb,
    const float* __restrict__ Wdbc, const float* __restrict__ Wdt,
    ushort* __restrict__ xn, ushort* __restrict__ Wpt, ushort* __restrict__ Wbt,
    ushort* __restrict__ Wdbct, ushort* __restrict__ WdtT)
{
    int blk = blockIdx.x;
    int tid = threadIdx.x;
    if (blk < 560) {
        __shared__ float tb[32 * 33];
        int xx = tid & 31, yy0 = tid >> 5;
        const float* in; ushort* outT; int K, N, bx, by;
        if (blk < 256)      { in = Wp;   outT = Wpt;   K = 512; N = 512; bx = (blk & 15) * 32; by = (blk >> 4) * 32; }
        else if (blk < 512) { int t = blk - 256; in = Wb; outT = Wbt; K = 512; N = 512; bx = (t & 15) * 32; by = (t >> 4) * 32; }
        else if (blk < 544) { int t = blk - 512; in = Wdbc; outT = Wdbct; K = 512; N = 64; bx = (t & 1) * 32; by = (t >> 1) * 32; }
        else                { int t = blk - 544; in = Wdt; outT = WdtT; K = 32; N = 512; bx = t * 32; by = 0; }
        #pragma unroll
        for (int yy = yy0; yy < 32; yy += 8)
            tb[yy * 33 + xx] = in[(size_t)(by + yy) * N + bx + xx];
        __syncthreads();
        #pragma unroll
        for (int yy = yy0; yy < 32; yy += 8)
            outT[(size_t)(bx + yy) * K + by + xx] = f2bf(tb[xx * 33 + yy]);
    } else {
        int bid = blk - 560;                 // 0..255
        int w = tid >> 6, lane = tid & 63;
        const float4* g4 = (const float4*)gamma;
        const float4* b4 = (const float4*)beta;
        float4 g0 = g4[lane], g1 = g4[lane + 64];
        float4 be0 = b4[lane], be1 = b4[lane + 64];
        for (int rr = 0; rr < 8; ++rr) {
            int row = bid * 32 + w * 8 + rr;
            const float4* xr = (const float4*)(x + (size_t)row * Ddim);
            float4 v0 = xr[lane];
            float4 v1 = xr[lane + 64];
            float s = v0.x + v0.y + v0.z + v0.w + v1.x + v1.y + v1.z + v1.w;
            float q = v0.x*v0.x + v0.y*v0.y + v0.z*v0.z + v0.w*v0.w
                    + v1.x*v1.x + v1.y*v1.y + v1.z*v1.z + v1.w*v1.w;
            #pragma unroll
            for (int m = 1; m <= 32; m <<= 1) { s += __shfl_xor(s, m); q += __shfl_xor(q, m); }
            float mu = s * (1.0f / Ddim);
            float var = q * (1.0f / Ddim) - mu * mu;
            float rs = rsqrtf(var + 1e-5f);
            ushort4 u0, u1;
            u0.x = f2bf((v0.x - mu) * rs * g0.x + be0.x);
            u0.y = f2bf((v0.y - mu) * rs * g0.y + be0.y);
            u0.z = f2bf((v0.z - mu) * rs * g0.z + be0.z);
            u0.w = f2bf((v0.w - mu) * rs * g0.w + be0.w);
            u1.x = f2bf((v1.x - mu) * rs * g1.x + be1.x);
            u1.y = f2bf((v1.y - mu) * rs * g1.y + be1.y);
            u1.z = f2bf((v1.z - mu) * rs * g1.z + be1.z);
            u1.w = f2bf((v1.w - mu) * rs * g1.w + be1.w);
            *(ushort4*)(xn + (size_t)row * Ddim + lane * 4) = u0;
            *(ushort4*)(xn + (size_t)row * Ddim + 256 + lane * 4) = u1;
        }
    }
}

// ---------------------------------------------------------------------------
// bf16 MFMA GEMM, 64x64 tile, BK=64, XOR-swizzled staging (round-6-proven
// gemm_wc64 structure, 0 bank conflicts). grid (M/64, N/64) = (128, 8):
// blockIdx.x = row-tile (fast) so same-A blocks land on one XCD.
// 1024 blocks -> 4 blocks/CU (vs 1 for 128-tiles): latency hiding.
// ---------------------------------------------------------------------------
__global__ __launch_bounds__(256) void gemm64(
    const ushort* __restrict__ A,   // [8192][512] bf16
    const ushort* __restrict__ Bt,  // [512][512] bf16 (W^T)
    const float* __restrict__ bias,
    ushort* __restrict__ Cb)        // [8192][512] bf16
{
    __shared__ __align__(16) ushort As[64 * 64];   // 8KB
    __shared__ __align__(16) ushort Bs[64 * 64];   // 8KB
    int tid = threadIdx.x, w = tid >> 6, lane = tid & 63;
    int bm = blockIdx.x * 64, bn = blockIdx.y * 64;
    int quad = lane >> 4, l16 = lane & 15;
    int srow8 = lane >> 3;
    int scolx = ((lane & 7) ^ srow8) * 8;          // swizzled global chunk
    int cof0 = (quad ^ (l16 & 7)) * 8;             // frag chunk, ks=0
    int cof1 = ((4 + quad) ^ (l16 & 7)) * 8;       // frag chunk, ks=1
    f32x4 acc[4] = {};

    for (int k0 = 0; k0 < 512; k0 += 64) {
        __syncthreads();
        #pragma unroll
        for (int s = 0; s < 2; ++s) {
            int r = w * 16 + s * 8;
            GLD16(A  + (size_t)(bm + r + srow8) * 512 + k0 + scolx, &As[r * 64]);
            GLD16(Bt + (size_t)(bn + r + srow8) * 512 + k0 + scolx, &Bs[r * 64]);
        }
        __syncthreads();
        #pragma unroll
        for (int ks = 0; ks < 2; ++ks) {
            int cof = ks ? cof1 : cof0;
            bf16x8 bfr = *(const bf16x8*)(const void*)&Bs[(w * 16 + l16) * 64 + cof];
            #pragma unroll
            for (int i = 0; i < 4; ++i) {
                bf16x8 af = *(const bf16x8*)(const void*)&As[(16 * i + l16) * 64 + cof];
                acc[i] = __builtin_amdgcn_mfma_f32_16x16x32_bf16(af, bfr, acc[i], 0, 0, 0);
            }
        }
    }
    int col = bn + w * 16 + l16;
    float bv = bias[col];
    #pragma unroll
    for (int i = 0; i < 4; ++i) {
        int row = bm + 16 * i + quad * 4;
        #pragma unroll
        for (int r = 0; r < 4; ++r)
            Cb[(size_t)(row + r) * 512 + col] = f2bf(acc[i][r] + bv);
    }
}

// ---------------------------------------------------------------------------
// Fused dbc + delta: per block, 32 token-rows.
// Phase A: dbc[32][64] = bwd @ Wdbc  (K=512, BK=64 swizzled) -> cols 0..31 to
// LDS (bf16), cols 32..63 to BC (fp32).
// Phase B: delta[32][512] = softplus(dbc_lds @ Wdt + b_dt), K=32 single MFMA.
// grid 256 blocks (1/CU).
// ---------------------------------------------------------------------------
__global__ __launch_bounds__(256) void dbc_delta(
    const ushort* __restrict__ bwd,   // [8192][512] bf16
    const ushort* __restrict__ Wdbct, // [64][512] bf16
    const ushort* __restrict__ WdtT,  // [512][32] bf16
    const float* __restrict__ b_dt,   // [512]
    float* __restrict__ BC,           // [8192][32] fp32
    ushort* __restrict__ delta)       // [8192][512] bf16
{
    __shared__ __align__(16) ushort As[32 * 64];    // 4KB
    __shared__ __align__(16) ushort Bs[64 * 64];    // 8KB (A) / [128][32] (B)
    __shared__ __align__(16) ushort sdbc[32 * 32];  // 2KB
    int tid = threadIdx.x, w = tid >> 6, lane = tid & 63;
    int bm = blockIdx.x * 32;
    int quad = lane >> 4, l16 = lane & 15;
    int srow8 = lane >> 3;
    int scolx = ((lane & 7) ^ srow8) * 8;
    int cof0 = (quad ^ (l16 & 7)) * 8;
    int cof1 = ((4 + quad) ^ (l16 & 7)) * 8;

    // -------- Phase A --------
    f32x4 acc[2] = {};
    for (int k0 = 0; k0 < 512; k0 += 64) {
        __syncthreads();
        {
            int r = w * 8;
            GLD16(bwd + (size_t)(bm + r + srow8) * 512 + k0 + scolx, &As[r * 64]);
        }
        #pragma unroll
        for (int s = 0; s < 2; ++s) {
            int r = w * 16 + s * 8;
            GLD16(Wdbct + (size_t)(r + srow8) * 512 + k0 + scolx, &Bs[r * 64]);
        }
        __syncthreads();
        #pragma unroll
        for (int ks = 0; ks < 2; ++ks) {
            int cof = ks ? cof1 : cof0;
            bf16x8 bfr = *(const bf16x8*)(const void*)&Bs[(w * 16 + l16) * 64 + cof];
            #pragma unroll
            for (int i = 0; i < 2; ++i) {
                bf16x8 af = *(const bf16x8*)(const void*)&As[(16 * i + l16) * 64 + cof];
                acc[i] = __builtin_amdgcn_mfma_f32_16x16x32_bf16(af, bfr, acc[i], 0, 0, 0);
            }
        }
    }
    {
        int col = w * 16 + l16;   // waves 0,1 -> dbc cols 0..31; waves 2,3 -> BC
        #pragma unroll
        for (int i = 0; i < 2; ++i) {
            int rl = 16 * i + quad * 4;
            #pragma unroll
            for (int r = 0; r < 4; ++r) {
                float v = acc[i][r];
                if (col < 32) sdbc[(rl + r) * 32 + col] = f2bf(v);
                else          BC[(size_t)(bm + rl + r) * 32 + col - 32] = v;
            }
        }
    }
    __syncthreads();
    // -------- Phase B --------
    bf16x8 af2[2];
    #pragma unroll
    for (int i = 0; i < 2; ++i)
        af2[i] = *(const bf16x8*)(const void*)&sdbc[(16 * i + l16) * 32 + quad * 8];
    int srow16 = lane >> 2, sch = (lane & 3) * 8;
    for (int cn = 0; cn < 4; ++cn) {
        __syncthreads();   // protect Bs reuse
        #pragma unroll
        for (int s = 0; s < 2; ++s) {
            int r = w * 32 + s * 16;
            GLD16(WdtT + (size_t)(cn * 128 + r + srow16) * 32 + sch, &Bs[r * 32]);
        }
        __syncthreads();
        #pragma unroll
        for (int j = 0; j < 2; ++j) {
            bf16x8 bfr = *(const bf16x8*)(const void*)&Bs[(w * 32 + j * 16 + l16) * 32 + quad * 8];
            f32x4 a2[2] = {};
            #pragma unroll
            for (int i = 0; i < 2; ++i)
                a2[i] = __builtin_amdgcn_mfma_f32_16x16x32_bf16(af2[i], bfr, a2[i], 0, 0, 0);
            int col = cn * 128 + w * 32 + j * 16 + l16;
            float bv = b_dt[col];
            #pragma unroll
            for (int i = 0; i < 2; ++i) {
                int row = bm + 16 * i + quad * 4;
                #pragma unroll
                for (int r = 0; r < 4; ++r)
                    delta[(size_t)(row + r) * 512 + col] = f2bf(softplus_f(a2[i][r] + bv));
            }
        }
    }
}

// ---------------------------------------------------------------------------
// Chunked parallel scan (round-8 proven, bf16 inputs).
// BC [TOK][32]: cols 0..15 = B, 16..31 = C.
// ---------------------------------------------------------------------------
__global__ __launch_bounds__(256) void scan_pass1(
    const ushort* __restrict__ delta, const ushort* __restrict__ bwd,
    const float* __restrict__ BC, const float* __restrict__ A_log,
    float* __restrict__ hend, float* __restrict__ sdbuf)
{
    int d = (blockIdx.x << 8) + threadIdx.x;
    int c = blockIdx.y;
    int b = blockIdx.z;

    float A[16];
    {
        const float4* al = (const float4*)(A_log + (size_t)d * 16);
        #pragma unroll
        for (int i = 0; i < 4; ++i) {
            float4 v = al[i];
            A[4*i+0] = -__expf(v.x); A[4*i+1] = -__expf(v.y);
            A[4*i+2] = -__expf(v.z); A[4*i+3] = -__expf(v.w);
        }
    }
    float h[16];
    #pragma unroll
    for (int n = 0; n < 16; ++n) h[n] = 0.f;
    float sd = 0.f;

    size_t base = ((size_t)(b * Sdim + c * LCh)) * Ddim + d;
    const float* bcrow = BC + ((size_t)(b * Sdim + c * LCh)) * 32;

    #pragma unroll 2
    for (int i = 0; i < LCh; ++i) {
        float dlt = bf2f(delta[base + (size_t)i * Ddim]);
        float bw  = bf2f(bwd [base + (size_t)i * Ddim]);
        float4 B0 = *(const float4*)(bcrow + i * 32 + 0);
        float4 B1 = *(const float4*)(bcrow + i * 32 + 4);
        float4 B2 = *(const float4*)(bcrow + i * 32 + 8);
        float4 B3 = *(const float4*)(bcrow + i * 32 + 12);
        sd += dlt;
        float xb = dlt * bw;
        float Bv[16] = {B0.x,B0.y,B0.z,B0.w, B1.x,B1.y,B1.z,B1.w,
                        B2.x,B2.y,B2.z,B2.w, B3.x,B3.y,B3.z,B3.w};
        #pragma unroll
        for (int n = 0; n < 16; ++n)
            h[n] = fmaf(__expf(dlt * A[n]), h[n], xb * Bv[n]);
    }
    size_t cidx = ((((size_t)b * NCh + c) * Ddim) + d) * 16;
    float4* ho = (float4*)(hend + cidx);
    ho[0] = make_float4(h[0],  h[1],  h[2],  h[3]);
    ho[1] = make_float4(h[4],  h[5],  h[6],  h[7]);
    ho[2] = make_float4(h[8],  h[9],  h[10], h[11]);
    ho[3] = make_float4(h[12], h[13], h[14], h[15]);
    sdbuf[((size_t)b * NCh + c) * Ddim + d] = sd;
}

__global__ __launch_bounds__(256) void scan_pass2(
    float* __restrict__ hend, const float* __restrict__ sdbuf,
    const float* __restrict__ A_log)
{
    int gl = blockIdx.x * 256 + threadIdx.x;
    int b = gl >> 13;
    int r = gl & 8191;
    int d = r >> 4;
    float A = -__expf(A_log[r]);
    float hin = 0.f;
    for (int c0 = 0; c0 < NCh; c0 += 8) {
        float he[8], dec[8];
        #pragma unroll
        for (int u = 0; u < 8; ++u) {
            size_t idx = (((size_t)b * NCh + c0 + u) * Ddim) * 16 + r;
            he[u]  = hend[idx];
            dec[u] = __expf(A * sdbuf[((size_t)b * NCh + c0 + u) * Ddim + d]);
        }
        #pragma unroll
        for (int u = 0; u < 8; ++u) {
            size_t idx = (((size_t)b * NCh + c0 + u) * Ddim) * 16 + r;
            hend[idx] = hin;
            hin = fmaf(dec[u], hin, he[u]);
        }
    }
}

__global__ __launch_bounds__(256) void scan_pass3(
    const ushort* __restrict__ delta, const ushort* __restrict__ bwd,
    const float* __restrict__ BC, const ushort* __restrict__ z1,
    const float* __restrict__ x, const float* __restrict__ A_log,
    const float* __restrict__ D_ssm, const float* __restrict__ hin,
    float* __restrict__ out)
{
    int d = (blockIdx.x << 8) + threadIdx.x;
    int c = blockIdx.y;
    int b = blockIdx.z;

    float A[16];
    {
        const float4* al = (const float4*)(A_log + (size_t)d * 16);
        #pragma unroll
        for (int i = 0; i < 4; ++i) {
            float4 v = al[i];
            A[4*i+0] = -__expf(v.x); A[4*i+1] = -__expf(v.y);
            A[4*i+2] = -__expf(v.z); A[4*i+3] = -__expf(v.w);
        }
    }
    float h[16];
    {
        size_t cidx = ((((size_t)b * NCh + c) * Ddim) + d) * 16;
        const float4* hi = (const float4*)(hin + cidx);
        float4 h0 = hi[0], h1 = hi[1], h2 = hi[2], h3 = hi[3];
        h[0]=h0.x; h[1]=h0.y; h[2]=h0.z; h[3]=h0.w;
        h[4]=h1.x; h[5]=h1.y; h[6]=h1.z; h[7]=h1.w;
        h[8]=h2.x; h[9]=h2.y; h[10]=h2.z; h[11]=h2.w;
        h[12]=h3.x; h[13]=h3.y; h[14]=h3.z; h[15]=h3.w;
    }
    float Dd = D_ssm[d];

    size_t base = ((size_t)(b * Sdim + c * LCh)) * Ddim + d;
    const float* bcrow = BC + ((size_t)(b * Sdim + c * LCh)) * 32;

    #pragma unroll 2
    for (int i = 0; i < LCh; ++i) {
        float dlt = bf2f(delta[base + (size_t)i * Ddim]);
        float bw  = bf2f(bwd [base + (size_t)i * Ddim]);
        float z1v = bf2f(z1  [base + (size_t)i * Ddim]);
        float xv  = x[base + (size_t)i * Ddim];
        float4 B0 = *(const float4*)(bcrow + i * 32 + 0);
        float4 B1 = *(const float4*)(bcrow + i * 32 + 4);
        float4 B2 = *(const float4*)(bcrow + i * 32 + 8);
        float4 B3 = *(const float4*)(bcrow + i * 32 + 12);
        float4 C0 = *(const float4*)(bcrow + i * 32 + 16);
        float4 C1 = *(const float4*)(bcrow + i * 32 + 20);
        float4 C2 = *(const float4*)(bcrow + i * 32 + 24);
        float4 C3 = *(const float4*)(bcrow + i * 32 + 28);
        float Bv[16] = {B0.x,B0.y,B0.z,B0.w, B1.x,B1.y,B1.z,B1.w,
                        B2.x,B2.y,B2.z,B2.w, B3.x,B3.y,B3.z,B3.w};
        float Cv[16] = {C0.x,C0.y,C0.z,C0.w, C1.x,C1.y,C1.z,C1.w,
                        C2.x,C2.y,C2.z,C2.w, C3.x,C3.y,C3.z,C3.w};
        float xb = dlt * bw;
        float y  = Dd * bw;
        #pragma unroll
        for (int n = 0; n < 16; ++n) {
            h[n] = fmaf(__expf(dlt * A[n]), h[n], xb * Bv[n]);
            y = fmaf(h[n], Cv[n], y);
        }
        float silu = z1v / (1.f + __expf(-z1v));
        out[base + (size_t)i * Ddim] = fmaf(z1v + y, silu, xv);
    }
}

// ---------------------------------------------------------------------------
extern "C" void kernel_launch(void* const* d_in, const int* in_sizes, int n_in,
                              void* d_out, int out_size, void* d_ws, size_t ws_size,
                              hipStream_t stream) {
    const float* x      = (const float*)d_in[0];
    const float* gamma  = (const float*)d_in[1];
    const float* beta   = (const float*)d_in[2];
    const float* W_proj = (const float*)d_in[3];
    const float* b_proj = (const float*)d_in[4];
    // d_in[5]=W_fwd, d_in[6]=b_fwd dead in reference (x1_ssm unused)
    const float* W_bwd  = (const float*)d_in[7];
    const float* b_bwd  = (const float*)d_in[8];
    const float* W_dbc  = (const float*)d_in[9];
    const float* W_dt   = (const float*)d_in[10];
    const float* b_dt   = (const float*)d_in[11];
    const float* A_log  = (const float*)d_in[12];
    const float* D_ssm  = (const float*)d_in[13];
    float* out = (float*)d_out;

    char* p = (char*)d_ws;
    ushort* xn_bf    = (ushort*)p;                        // 8 MB  [0,8M)
    ushort* z1_bf    = (ushort*)(p + (8ull  << 20));      // 8 MB
    ushort* bwd_bf   = (ushort*)(p + (16ull << 20));      // 8 MB
    ushort* delta_bf = (ushort*)(p + (24ull << 20));      // 8 MB
    float*  BC       = (float*) (p + (33ull << 20));      // 1 MB   [8192][32]
    float*  hend     = (float*) (p + (34ull << 20));      // 8 MB
    float*  sdbuf    = (float*) (p + (42ull << 20));      // 0.5 MB
    ushort* Wpt      = (ushort*)(p + (43ull << 20));      // 0.5 MB
    ushort* Wbt      = Wpt   + (size_t)512 * 512;         // 0.5 MB
    ushort* Wdbct    = Wbt   + (size_t)512 * 512;         // 64 KB  [64][512]
    ushort* WdtT     = Wdbct + (size_t)64 * 512;          // 32 KB  [512][32]

    // 1. prep: transposes + LayerNorm (one dispatch)
    prep_all<<<dim3(816), dim3(256), 0, stream>>>(
        x, gamma, beta, W_proj, W_bwd, W_dbc, W_dt, xn_bf, Wpt, Wbt, Wdbct, WdtT);
    // 2. z1 = xn @ Wp + bp   (64x64 tiles, 1024 blocks)
    gemm64<<<dim3(128, 8), dim3(256), 0, stream>>>(xn_bf, Wpt, b_proj, z1_bf);
    // 3. bwd = z1 @ Wb + bb
    gemm64<<<dim3(128, 8), dim3(256), 0, stream>>>(z1_bf, Wbt, b_bwd, bwd_bf);
    // 4. fused [dbc|BC] + delta
    dbc_delta<<<dim3(256), dim3(256), 0, stream>>>(bwd_bf, Wdbct, WdtT, b_dt, BC, delta_bf);
    // 5-7. chunked scan
    scan_pass1<<<dim3(2, NCh, Bb), dim3(256), 0, stream>>>(delta_bf, bwd_bf, BC, A_log, hend, sdbuf);
    scan_pass2<<<dim3(128), dim3(256), 0, stream>>>(hend, sdbuf, A_log);
    scan_pass3<<<dim3(2, NCh, Bb), dim3(256), 0, stream>>>(delta_bf, bwd_bf, BC, z1_bf, x, A_log, D_ssm, hend, out);
}